// Round 3
// baseline (430.240 us; speedup 1.0000x reference)
//
#include <hip/hip_runtime.h>
#include <math.h>

#define SEQ   100
#define NREP  8
#define FFD   2048
#define NBLK  256
#define RSQRT2 0.70710678118654752440f

__device__ __forceinline__ float wsum(float v) {
#pragma unroll
  for (int o = 32; o > 0; o >>= 1) v += __shfl_xor(v, o, 64);
  return v;
}

// grid-wide barrier: self-resetting generation barrier, agent scope.
// Safe: 256 blocks x 1024 thr (<=128 VGPR enforced by launch bounds) -> 1
// block/CU on 256 CUs, all resident simultaneously.
__device__ __forceinline__ void gbar(unsigned* cnt, unsigned* gen) {
  __syncthreads();                       // all waves drain vmem + rendezvous
  if (threadIdx.x == 0) {
    __threadfence();                     // release: L2 writeback (cross-XCD)
    unsigned g0 = __hip_atomic_load(gen, __ATOMIC_RELAXED, __HIP_MEMORY_SCOPE_AGENT);
    unsigned a  = __hip_atomic_fetch_add(cnt, 1u, __ATOMIC_ACQ_REL, __HIP_MEMORY_SCOPE_AGENT);
    if (a == (unsigned)(NBLK - 1)) {
      __hip_atomic_store(cnt, 0u, __ATOMIC_RELAXED, __HIP_MEMORY_SCOPE_AGENT);
      __hip_atomic_fetch_add(gen, 1u, __ATOMIC_RELEASE, __HIP_MEMORY_SCOPE_AGENT);
    } else {
      while (__hip_atomic_load(gen, __ATOMIC_ACQUIRE, __HIP_MEMORY_SCOPE_AGENT) == g0)
        __builtin_amdgcn_s_sleep(2);
    }
    __threadfence();                     // acquire: invalidate L1/L2
  }
  __syncthreads();
}

__global__ __launch_bounds__(1024) void k_fused(
    const float* __restrict__ x,
    const float* __restrict__ convw, const float* __restrict__ convb,
    const float* __restrict__ Wl,  const float* __restrict__ bl,
    const float* __restrict__ lng, const float* __restrict__ lnb,
    const float* __restrict__ Win, const float* __restrict__ bi,
    const float* __restrict__ Wout,const float* __restrict__ bout,
    const float* __restrict__ W1,  const float* __restrict__ b1,
    const float* __restrict__ W2,  const float* __restrict__ b2,
    const float* __restrict__ g1,  const float* __restrict__ be1,
    const float* __restrict__ g2,  const float* __restrict__ be2,
    float* __restrict__ X, float* __restrict__ O,
    unsigned* __restrict__ barc, unsigned* __restrict__ barg,
    float* __restrict__ out)
{
  __shared__ float2 kvs[4][256];      // per-attn-group k/v
  __shared__ float  kred[4][4][2];    // per-group wave partial max/min
  __shared__ float  x1s[100][4];      // post-LN1 rows for this batch
  __shared__ float  pacc[16][100][4]; // ffn partial accumulators

  const int t    = threadIdx.x;
  const int b    = blockIdx.x;
  const int lane = t & 63;
  const int wv   = t >> 6;

  // ================= stage A: 1 wave per block, lane<50 owns rows 2l,2l+1
  if (t < 64) {
    const float cw = convw[0], cb = convb[0];
    float W[4][4], B[4];
#pragma unroll
    for (int j = 0; j < 4; ++j) {
      B[j] = bl[j];
#pragma unroll
      for (int d = 0; d < 4; ++d) W[j][d] = Wl[j * 4 + d];
    }
    const bool act = lane < 50;
    float h[2][4] = {{0.f,0.f,0.f,0.f},{0.f,0.f,0.f,0.f}};
    float gg[2][4] = {{0.f}}, eb[2][4] = {{0.f}};
    if (act) {
#pragma unroll
      for (int p = 0; p < 2; ++p) {
        const int r = lane * 2 + p;
        float4 xr = *(const float4*)(x + (b * SEQ + r) * 4);
        h[p][0] = fmaf(xr.x, cw, cb); h[p][1] = fmaf(xr.y, cw, cb);
        h[p][2] = fmaf(xr.z, cw, cb); h[p][3] = fmaf(xr.w, cw, cb);
        float4 gv = *(const float4*)(lng + r * 4);
        float4 bv = *(const float4*)(lnb + r * 4);
        gg[p][0] = gv.x; gg[p][1] = gv.y; gg[p][2] = gv.z; gg[p][3] = gv.w;
        eb[p][0] = bv.x; eb[p][1] = bv.y; eb[p][2] = bv.z; eb[p][3] = bv.w;
      }
    }
    for (int it = 0; it < NREP; ++it) {
      float y[2][4] = {{0.f,0.f,0.f,0.f},{0.f,0.f,0.f,0.f}};
      float s1 = 0.f, s2 = 0.f;
      if (act) {
#pragma unroll
        for (int p = 0; p < 2; ++p)
#pragma unroll
          for (int j = 0; j < 4; ++j) {
            float yy = B[j];
#pragma unroll
            for (int d = 0; d < 4; ++d) yy = fmaf(h[p][d], W[j][d], yy);
            y[p][j] = yy; s1 += yy; s2 = fmaf(yy, yy, s2);
          }
      }
      s1 = wsum(s1); s2 = wsum(s2);
      const float mean = s1 * (1.0f / 400.0f);
      const float var  = s2 * (1.0f / 400.0f) - mean * mean;
      const float rstd = rsqrtf(var + 1e-5f);
      if (act) {
#pragma unroll
        for (int p = 0; p < 2; ++p)
#pragma unroll
          for (int j = 0; j < 4; ++j) {
            float vv = fmaf((y[p][j] - mean) * rstd, gg[p][j], eb[p][j]);
            h[p][j] = 0.5f * vv * (1.0f + erff(vv * RSQRT2));
          }
      }
    }
    if (act) {
#pragma unroll
      for (int p = 0; p < 2; ++p) {
        float yy[4];
#pragma unroll
        for (int j = 0; j < 4; ++j) {
          float a = B[j];
#pragma unroll
          for (int d = 0; d < 4; ++d) a = fmaf(h[p][d], W[j][d], a);
          yy[j] = a;
        }
        *(float4*)(X + (b * SEQ + lane * 2 + p) * 4) =
            make_float4(yy[0], yy[1], yy[2], yy[3]);
      }
    }
  }
  gbar(barc, barg);

  // ================= 4 encoder layers
  for (int l = 0; l < 4; ++l) {
    // ---------- attention: 2 active 256-thread groups per block
    {
      const float* Wa = Win + l * 48;
      const float* ba = bi + l * 12;
      const int g    = t >> 8;            // group 0..3
      const int s    = t & 255;           // query/key index
      const int slot = b + 256 * g;       // (n,h) slot
      const int sc   = slot < 400 ? slot : 399;
      const int n    = sc % 100;
      const int hd   = sc / 100;
      float4 xr = *(const float4*)(X + (s * SEQ + n) * 4);
      const float* wq = Wa + hd * 4;
      const float* wk = Wa + (4 + hd) * 4;
      const float* wvp = Wa + (8 + hd) * 4;
      float q = ba[hd]   + xr.x*wq[0] + xr.y*wq[1] + xr.z*wq[2] + xr.w*wq[3];
      float k = ba[4+hd] + xr.x*wk[0] + xr.y*wk[1] + xr.z*wk[2] + xr.w*wk[3];
      float v = ba[8+hd] + xr.x*wvp[0]+ xr.y*wvp[1]+ xr.z*wvp[2]+ xr.w*wvp[3];
      kvs[g][s] = make_float2(k, v);
      float kmx = k, kmn = k;
#pragma unroll
      for (int o = 32; o > 0; o >>= 1) {
        kmx = fmaxf(kmx, __shfl_xor(kmx, o, 64));
        kmn = fminf(kmn, __shfl_xor(kmn, o, 64));
      }
      if ((t & 63) == 0) { kred[g][(t >> 6) & 3][0] = kmx; kred[g][(t >> 6) & 3][1] = kmn; }
      __syncthreads();
      if (slot < 400) {                   // wave-uniform: inactive waves skip
        kmx = fmaxf(fmaxf(kred[g][0][0], kred[g][1][0]),
                    fmaxf(kred[g][2][0], kred[g][3][0]));
        kmn = fminf(fminf(kred[g][0][1], kred[g][1][1]),
                    fminf(kred[g][2][1], kred[g][3][1]));
        const float m = (q >= 0.f) ? q * kmx : q * kmn;  // exact max_t(q*k_t)
        float den = 0.f, num = 0.f;
#pragma unroll 8
        for (int t2 = 0; t2 < 256; ++t2) {
          float2 kt = kvs[g][t2];
          float p = __expf(fmaf(q, kt.x, -m));
          den += p;
          num = fmaf(p, kt.y, num);
        }
        O[(s * SEQ + n) * 4 + hd] = num / den;
      }
    }
    gbar(barc, barg);

    // ---------- proj + LN1 + FFN + LN2 (block b owns batch b, 100 rows)
    {
      const float* W1l = W1 + l * FFD * 4;
      const float* b1l = b1 + l * FFD;
      const float* W2l = W2 + l * 4 * FFD;
      const float* b2l = b2 + l * 4;
      const float* Wo  = Wout + l * 16;
      const float* bo  = bout + l * 4;
      const float* g1l = g1 + l * 4;  const float* e1l = be1 + l * 4;
      const float* g2l = g2 + l * 4;  const float* e2l = be2 + l * 4;

      if (t < 100) {
        const int gr = b * SEQ + t;
        float4 xr = *(const float4*)(X + gr * 4);
        float4 od = *(const float4*)(O + gr * 4);
        float xv[4] = {xr.x, xr.y, xr.z, xr.w};
        float ov[4] = {od.x, od.y, od.z, od.w};
        float rr[4];
#pragma unroll
        for (int d = 0; d < 4; ++d) {
          float op = bo[d];
#pragma unroll
          for (int e = 0; e < 4; ++e) op = fmaf(ov[e], Wo[d * 4 + e], op);
          rr[d] = xv[d] + op;
        }
        float mean = 0.25f * (rr[0] + rr[1] + rr[2] + rr[3]);
        float var = 0.f;
#pragma unroll
        for (int d = 0; d < 4; ++d) { float dv = rr[d] - mean; var = fmaf(dv, dv, var); }
        float rstd = rsqrtf(0.25f * var + 1e-5f);
#pragma unroll
        for (int d = 0; d < 4; ++d)
          x1s[t][d] = fmaf((rr[d] - mean) * rstd, g1l[d], e1l[d]);
      }
      __syncthreads();

      // wave wv covers f in [wv*128,(wv+1)*128); lane = rowA, lane<36 also rowB
      const int fb = __builtin_amdgcn_readfirstlane(wv) * 128;
      const int rB = 64 + (lane < 36 ? lane : 35);
      const float xA0 = x1s[lane][0], xA1 = x1s[lane][1];
      const float xA2 = x1s[lane][2], xA3 = x1s[lane][3];
      const float xB0 = x1s[rB][0], xB1 = x1s[rB][1];
      const float xB2 = x1s[rB][2], xB3 = x1s[rB][3];
      float aA0=0.f,aA1=0.f,aA2=0.f,aA3=0.f;
      float aB0=0.f,aB1=0.f,aB2=0.f,aB3=0.f;
#pragma unroll 4
      for (int j = 0; j < 128; ++j) {
        const int f = fb + j;                       // wave-uniform -> s_load
        const float4 w1v = *(const float4*)(W1l + f * 4);
        const float bb  = b1l[f];
        const float w20 = W2l[f],           w21 = W2l[FFD + f];
        const float w22 = W2l[2 * FFD + f], w23 = W2l[3 * FFD + f];
        float hA = fmaf(xA3, w1v.w, fmaf(xA2, w1v.z, fmaf(xA1, w1v.y, fmaf(xA0, w1v.x, bb))));
        hA = fmaxf(hA, 0.f);
        aA0 = fmaf(hA, w20, aA0); aA1 = fmaf(hA, w21, aA1);
        aA2 = fmaf(hA, w22, aA2); aA3 = fmaf(hA, w23, aA3);
        float hB = fmaf(xB3, w1v.w, fmaf(xB2, w1v.z, fmaf(xB1, w1v.y, fmaf(xB0, w1v.x, bb))));
        hB = fmaxf(hB, 0.f);
        aB0 = fmaf(hB, w20, aB0); aB1 = fmaf(hB, w21, aB1);
        aB2 = fmaf(hB, w22, aB2); aB3 = fmaf(hB, w23, aB3);
      }
      *(float4*)&pacc[wv][lane][0] = make_float4(aA0, aA1, aA2, aA3);
      if (lane < 36)
        *(float4*)&pacc[wv][64 + lane][0] = make_float4(aB0, aB1, aB2, aB3);
      __syncthreads();

      if (t < 400) {
        const int r = t >> 2, d = t & 3;
        float sacc = b2l[d];
#pragma unroll
        for (int w = 0; w < 16; ++w) sacc += pacc[w][r][d];
        float val = x1s[r][d] + sacc;
        float sum = val + __shfl_xor(val, 1, 64); sum += __shfl_xor(sum, 2, 64);
        const float mean = 0.25f * sum;
        const float dv = val - mean;
        float qq = dv * dv;
        float qs = qq + __shfl_xor(qq, 1, 64); qs += __shfl_xor(qs, 2, 64);
        const float rstd = rsqrtf(0.25f * qs + 1e-5f);
        X[(b * SEQ + r) * 4 + d] = fmaf(dv * rstd, g2l[d], e2l[d]);
      }
    }
    if (l < 3) gbar(barc, barg);
    else __syncthreads();   // final only reads this block's own rows
  }

  // ================= final linear + softmax over d
  if (t < 100) {
    const int gr = b * SEQ + t;
    float4 xr = *(const float4*)(X + gr * 4);
    float xv[4] = {xr.x, xr.y, xr.z, xr.w};
    float y[4];
#pragma unroll
    for (int j = 0; j < 4; ++j) {
      float yy = bl[j];
#pragma unroll
      for (int d = 0; d < 4; ++d) yy = fmaf(xv[d], Wl[j * 4 + d], yy);
      y[j] = yy;
    }
    float m = fmaxf(fmaxf(y[0], y[1]), fmaxf(y[2], y[3]));
    float e[4], s = 0.f;
#pragma unroll
    for (int j = 0; j < 4; ++j) { e[j] = __expf(y[j] - m); s += e[j]; }
    const float inv = 1.0f / s;
    *(float4*)(out + gr * 4) = make_float4(e[0]*inv, e[1]*inv, e[2]*inv, e[3]*inv);
  }
}

// ---------------------------------------------------------------- launch
extern "C" void kernel_launch(void* const* d_in, const int* in_sizes, int n_in,
                              void* d_out, int out_size, void* d_ws, size_t ws_size,
                              hipStream_t stream)
{
  const float* x     = (const float*)d_in[0];
  const float* convw = (const float*)d_in[1];
  const float* convb = (const float*)d_in[2];
  const float* Wl    = (const float*)d_in[3];
  const float* bl    = (const float*)d_in[4];
  const float* lng   = (const float*)d_in[5];
  const float* lnb   = (const float*)d_in[6];
  const float* Win   = (const float*)d_in[7];
  const float* bi    = (const float*)d_in[8];
  const float* Wout  = (const float*)d_in[9];
  const float* bout  = (const float*)d_in[10];
  const float* W1    = (const float*)d_in[11];
  const float* b1    = (const float*)d_in[12];
  const float* W2    = (const float*)d_in[13];
  const float* b2    = (const float*)d_in[14];
  const float* g1    = (const float*)d_in[15];
  const float* be1   = (const float*)d_in[16];
  const float* g2    = (const float*)d_in[17];
  const float* be2   = (const float*)d_in[18];

  float* X = (float*)d_ws;                       // [256*100*4]
  float* O = X + 256 * SEQ * 4;                  // [256*100*4]
  unsigned* bar = (unsigned*)((char*)d_ws + (1 << 20));
  hipMemsetAsync(bar, 0, 8, stream);             // barrier state: deterministic per call

  k_fused<<<NBLK, 1024, 0, stream>>>(x, convw, convb, Wl, bl, lng, lnb,
                                     Win, bi, Wout, bout, W1, b1, W2, b2,
                                     g1, be1, g2, be2, X, O, bar, bar + 1,
                                     (float*)d_out);
}

// Round 4
// 187.213 us; speedup vs baseline: 2.2981x; 2.2981x over previous
//
#include <hip/hip_runtime.h>
#include <math.h>

#define SEQ   100
#define BATCH 256
#define NREP  8
#define FFD   2048
#define RSQRT2 0.70710678118654752440f

__device__ __forceinline__ float wsum(float v) {
#pragma unroll
  for (int o = 32; o > 0; o >>= 1) v += __shfl_xor(v, o, 64);
  return v;
}

// ---------------------------------------------------------------- stage A
// one block (1 wave) per batch element b; lane<50 owns rows 2l, 2l+1.
// h = x*cw+cb; 8x { h = gelu(LN_[100,4](h@Wl.T+bl)*g+b) }; XT[n][b] = h@Wl.T+bl
__global__ __launch_bounds__(64) void k_stageA(
    const float* __restrict__ x, const float* __restrict__ convw,
    const float* __restrict__ convb, const float* __restrict__ Wl,
    const float* __restrict__ bl, const float* __restrict__ lng,
    const float* __restrict__ lnb, float* __restrict__ XT)
{
  const int b = blockIdx.x;
  const int lane = threadIdx.x;
  const bool act = lane < 50;

  const float cw = convw[0], cb = convb[0];
  float W[4][4], B[4];
#pragma unroll
  for (int j = 0; j < 4; ++j) {
    B[j] = bl[j];
#pragma unroll
    for (int d = 0; d < 4; ++d) W[j][d] = Wl[j * 4 + d];
  }

  float h[2][4] = {{0.f,0.f,0.f,0.f},{0.f,0.f,0.f,0.f}};
  float gg[2][4] = {{0.f}}, eb[2][4] = {{0.f}};
  if (act) {
#pragma unroll
    for (int p = 0; p < 2; ++p) {
      const int r = lane * 2 + p;
      float4 xr = *(const float4*)(x + (b * SEQ + r) * 4);
      h[p][0] = fmaf(xr.x, cw, cb); h[p][1] = fmaf(xr.y, cw, cb);
      h[p][2] = fmaf(xr.z, cw, cb); h[p][3] = fmaf(xr.w, cw, cb);
      float4 gv = *(const float4*)(lng + r * 4);
      float4 bv = *(const float4*)(lnb + r * 4);
      gg[p][0] = gv.x; gg[p][1] = gv.y; gg[p][2] = gv.z; gg[p][3] = gv.w;
      eb[p][0] = bv.x; eb[p][1] = bv.y; eb[p][2] = bv.z; eb[p][3] = bv.w;
    }
  }
  for (int it = 0; it < NREP; ++it) {
    float y[2][4] = {{0.f,0.f,0.f,0.f},{0.f,0.f,0.f,0.f}};
    float s1 = 0.f, s2 = 0.f;
    if (act) {
#pragma unroll
      for (int p = 0; p < 2; ++p)
#pragma unroll
        for (int j = 0; j < 4; ++j) {
          float yy = B[j];
#pragma unroll
          for (int d = 0; d < 4; ++d) yy = fmaf(h[p][d], W[j][d], yy);
          y[p][j] = yy; s1 += yy; s2 = fmaf(yy, yy, s2);
        }
    }
    s1 = wsum(s1); s2 = wsum(s2);
    const float mean = s1 * (1.0f / 400.0f);
    const float var  = s2 * (1.0f / 400.0f) - mean * mean;
    const float rstd = rsqrtf(var + 1e-5f);
    if (act) {
#pragma unroll
      for (int p = 0; p < 2; ++p)
#pragma unroll
        for (int j = 0; j < 4; ++j) {
          float vv = fmaf((y[p][j] - mean) * rstd, gg[p][j], eb[p][j]);
          h[p][j] = 0.5f * vv * (1.0f + erff(vv * RSQRT2));
        }
    }
  }
  if (act) {
#pragma unroll
    for (int p = 0; p < 2; ++p) {
      const int r = lane * 2 + p;
      float yy[4];
#pragma unroll
      for (int j = 0; j < 4; ++j) {
        float a = B[j];
#pragma unroll
        for (int d = 0; d < 4; ++d) a = fmaf(h[p][d], W[j][d], a);
        yy[j] = a;
      }
      // transposed: XT[n=r][s=b]
      *(float4*)(XT + (r * BATCH + b) * 4) =
          make_float4(yy[0], yy[1], yy[2], yy[3]);
    }
  }
}

// ---------------------------------------------------------------- encoder
// one block per column n (100 blocks x 1024 threads). Entire 4-layer
// encoder + final linear/softmax for this column, state in LDS only.
__global__ __launch_bounds__(1024) void k_encoder(
    const float* __restrict__ XT,
    const float* __restrict__ Win, const float* __restrict__ bi,
    const float* __restrict__ Wout, const float* __restrict__ bout,
    const float* __restrict__ W1,  const float* __restrict__ b1,
    const float* __restrict__ W2,  const float* __restrict__ b2,
    const float* __restrict__ g1,  const float* __restrict__ be1,
    const float* __restrict__ g2,  const float* __restrict__ be2,
    const float* __restrict__ Wl,  const float* __restrict__ bl,
    float* __restrict__ out)
{
  const int n    = blockIdx.x;   // seq position 0..99
  const int t    = threadIdx.x;
  const int lane = t & 63;
  const int wv   = t >> 6;

  __shared__ float  xs[256][4];        // current rows (s = batch idx)
  __shared__ float2 kv2[4][256];       // per-head (k,v)
  __shared__ float  qsm[4][256];       // per-head q
  __shared__ float  osm[4][256];       // per-head attn out
  __shared__ float  kred[4][4][2];     // per-head wave partial max/min
  __shared__ float  pacc[16][256][4];  // ffn partials (64 KB)

  if (t < 256) {
    float4 v = *(const float4*)(XT + (n * BATCH + t) * 4);
    xs[t][0] = v.x; xs[t][1] = v.y; xs[t][2] = v.z; xs[t][3] = v.w;
  }
  __syncthreads();

  for (int l = 0; l < 4; ++l) {
    const float* Wa  = Win + l * 48;
    const float* ba  = bi + l * 12;
    const float* Wo  = Wout + l * 16;
    const float* bo  = bout + l * 4;
    const float* W1l = W1 + l * FFD * 4;
    const float* b1l = b1 + l * FFD;
    const float* W2l = W2 + l * 4 * FFD;
    const float* b2l = b2 + l * 4;
    const float* g1l = g1 + l * 4;  const float* e1l = be1 + l * 4;
    const float* g2l = g2 + l * 4;  const float* e2l = be2 + l * 4;

    // ---- QKV (threads 0..255, row s=t)
    if (t < 256) {
      const float x0 = xs[t][0], x1 = xs[t][1], x2 = xs[t][2], x3 = xs[t][3];
#pragma unroll
      for (int h = 0; h < 4; ++h) {
        const float* wq = Wa + h * 4;
        const float* wk = Wa + (4 + h) * 4;
        const float* wvp = Wa + (8 + h) * 4;
        float q = ba[h]     + x0*wq[0] + x1*wq[1] + x2*wq[2] + x3*wq[3];
        float k = ba[4 + h] + x0*wk[0] + x1*wk[1] + x2*wk[2] + x3*wk[3];
        float v = ba[8 + h] + x0*wvp[0]+ x1*wvp[1]+ x2*wvp[2]+ x3*wvp[3];
        qsm[h][t] = q;
        kv2[h][t] = make_float2(k, v);
      }
    }
    __syncthreads();

    // ---- attention: thread (h = t>>8, s = t&255)
    {
      const int h = t >> 8, s = t & 255;
      float k = kv2[h][s].x;
      float kmx = k, kmn = k;
#pragma unroll
      for (int o = 32; o > 0; o >>= 1) {
        kmx = fmaxf(kmx, __shfl_xor(kmx, o, 64));
        kmn = fminf(kmn, __shfl_xor(kmn, o, 64));
      }
      if (lane == 0) { kred[h][s >> 6][0] = kmx; kred[h][s >> 6][1] = kmn; }
      __syncthreads();
      kmx = fmaxf(fmaxf(kred[h][0][0], kred[h][1][0]),
                  fmaxf(kred[h][2][0], kred[h][3][0]));
      kmn = fminf(fminf(kred[h][0][1], kred[h][1][1]),
                  fminf(kred[h][2][1], kred[h][3][1]));
      const float q = qsm[h][s];
      const float m = (q >= 0.f) ? q * kmx : q * kmn;   // exact max_t(q*k_t)
      float den0 = 0.f, den1 = 0.f, num0 = 0.f, num1 = 0.f;
#pragma unroll 4
      for (int t2 = 0; t2 < 256; t2 += 2) {
        float2 a = kv2[h][t2];
        float2 c = kv2[h][t2 + 1];
        float p0 = __expf(fmaf(q, a.x, -m));
        float p1 = __expf(fmaf(q, c.x, -m));
        den0 += p0; num0 = fmaf(p0, a.y, num0);
        den1 += p1; num1 = fmaf(p1, c.y, num1);
      }
      osm[h][s] = (num0 + num1) / (den0 + den1);
    }
    __syncthreads();

    // ---- Wout proj + residual + LN1 (threads 0..255) -> xs
    if (t < 256) {
      float ov[4] = {osm[0][t], osm[1][t], osm[2][t], osm[3][t]};
      float rr[4];
#pragma unroll
      for (int d = 0; d < 4; ++d) {
        float op = bo[d];
#pragma unroll
        for (int e = 0; e < 4; ++e) op = fmaf(ov[e], Wo[d * 4 + e], op);
        rr[d] = xs[t][d] + op;
      }
      float mean = 0.25f * (rr[0] + rr[1] + rr[2] + rr[3]);
      float var = 0.f;
#pragma unroll
      for (int d = 0; d < 4; ++d) { float dv = rr[d] - mean; var = fmaf(dv, dv, var); }
      float rstd = rsqrtf(0.25f * var + 1e-5f);
#pragma unroll
      for (int d = 0; d < 4; ++d)
        xs[t][d] = fmaf((rr[d] - mean) * rstd, g1l[d], e1l[d]);
    }
    __syncthreads();

    // ---- FFN: wave wv owns f in [wv*128, wv*128+128); lane owns rows
    //      {lane, lane+64, lane+128, lane+192}; wave-uniform weights -> s_load
    {
      const int fb = __builtin_amdgcn_readfirstlane(wv) * 128;
      float xr[4][4];
#pragma unroll
      for (int rg = 0; rg < 4; ++rg) {
        const int s = rg * 64 + lane;
        xr[rg][0] = xs[s][0]; xr[rg][1] = xs[s][1];
        xr[rg][2] = xs[s][2]; xr[rg][3] = xs[s][3];
      }
      float acc[4][4] = {{0.f,0.f,0.f,0.f},{0.f,0.f,0.f,0.f},
                         {0.f,0.f,0.f,0.f},{0.f,0.f,0.f,0.f}};
#pragma unroll 2
      for (int j = 0; j < 128; ++j) {
        const int f = fb + j;
        const float4 w1 = *(const float4*)(W1l + f * 4);
        const float bb  = b1l[f];
        const float w20 = W2l[f],           w21 = W2l[FFD + f];
        const float w22 = W2l[2 * FFD + f], w23 = W2l[3 * FFD + f];
#pragma unroll
        for (int rg = 0; rg < 4; ++rg) {
          float hh = fmaf(xr[rg][3], w1.w, fmaf(xr[rg][2], w1.z,
                     fmaf(xr[rg][1], w1.y, fmaf(xr[rg][0], w1.x, bb))));
          hh = fmaxf(hh, 0.f);
          acc[rg][0] = fmaf(hh, w20, acc[rg][0]);
          acc[rg][1] = fmaf(hh, w21, acc[rg][1]);
          acc[rg][2] = fmaf(hh, w22, acc[rg][2]);
          acc[rg][3] = fmaf(hh, w23, acc[rg][3]);
        }
      }
#pragma unroll
      for (int rg = 0; rg < 4; ++rg)
        *(float4*)&pacc[wv][rg * 64 + lane][0] =
            make_float4(acc[rg][0], acc[rg][1], acc[rg][2], acc[rg][3]);
    }
    __syncthreads();

    // ---- reduce partials + residual + LN2 (thread t -> (s,d))
    {
      const int s = t >> 2, d = t & 3;
      float sacc = b2l[d];
#pragma unroll
      for (int w = 0; w < 16; ++w) sacc += pacc[w][s][d];
      float val = xs[s][d] + sacc;
      float sum = val + __shfl_xor(val, 1, 64); sum += __shfl_xor(sum, 2, 64);
      const float mean = 0.25f * sum;
      const float dv = val - mean;
      float qq = dv * dv;
      float q2 = qq + __shfl_xor(qq, 1, 64); q2 += __shfl_xor(q2, 2, 64);
      const float rstd = rsqrtf(0.25f * q2 + 1e-5f);
      xs[s][d] = fmaf(dv * rstd, g2l[d], e2l[d]);  // own element only: no race
    }
    __syncthreads();
  }

  // ---- final linear + softmax over d; out[b=t][n]
  if (t < 256) {
    const float x0 = xs[t][0], x1 = xs[t][1], x2 = xs[t][2], x3 = xs[t][3];
    float y[4];
#pragma unroll
    for (int j = 0; j < 4; ++j)
      y[j] = fmaf(x3, Wl[j*4+3], fmaf(x2, Wl[j*4+2],
             fmaf(x1, Wl[j*4+1], fmaf(x0, Wl[j*4+0], bl[j]))));
    float m = fmaxf(fmaxf(y[0], y[1]), fmaxf(y[2], y[3]));
    float e[4], ssum = 0.f;
#pragma unroll
    for (int j = 0; j < 4; ++j) { e[j] = __expf(y[j] - m); ssum += e[j]; }
    const float inv = 1.0f / ssum;
    *(float4*)(out + (t * SEQ + n) * 4) =
        make_float4(e[0]*inv, e[1]*inv, e[2]*inv, e[3]*inv);
  }
}

// ---------------------------------------------------------------- launch
extern "C" void kernel_launch(void* const* d_in, const int* in_sizes, int n_in,
                              void* d_out, int out_size, void* d_ws, size_t ws_size,
                              hipStream_t stream)
{
  const float* x     = (const float*)d_in[0];
  const float* convw = (const float*)d_in[1];
  const float* convb = (const float*)d_in[2];
  const float* Wl    = (const float*)d_in[3];
  const float* bl    = (const float*)d_in[4];
  const float* lng   = (const float*)d_in[5];
  const float* lnb   = (const float*)d_in[6];
  const float* Win   = (const float*)d_in[7];
  const float* bi    = (const float*)d_in[8];
  const float* Wout  = (const float*)d_in[9];
  const float* bout  = (const float*)d_in[10];
  const float* W1    = (const float*)d_in[11];
  const float* b1    = (const float*)d_in[12];
  const float* W2    = (const float*)d_in[13];
  const float* b2    = (const float*)d_in[14];
  const float* g1    = (const float*)d_in[15];
  const float* be1   = (const float*)d_in[16];
  const float* g2    = (const float*)d_in[17];
  const float* be2   = (const float*)d_in[18];

  float* XT = (float*)d_ws;   // [100][256][4] floats = 400 KB

  k_stageA<<<BATCH, 64, 0, stream>>>(x, convw, convb, Wl, bl, lng, lnb, XT);
  k_encoder<<<SEQ, 1024, 0, stream>>>(XT, Win, bi, Wout, bout, W1, b1,
                                      W2, b2, g1, be1, g2, be2, Wl, bl,
                                      (float*)d_out);
}

// Round 5
// 132.558 us; speedup vs baseline: 3.2457x; 1.4123x over previous
//
#include <hip/hip_runtime.h>
#include <math.h>

#define SEQ   100
#define BATCH 256
#define NREP  8
#define FFD   2048
#define RSQRT2 0.70710678118654752440f

__device__ __forceinline__ float wsum(float v) {
#pragma unroll
  for (int o = 32; o > 0; o >>= 1) v += __shfl_xor(v, o, 64);
  return v;
}

// ---------------------------------------------------------------- stage A
// one block (1 wave) per batch element b; lane<50 owns rows 2l, 2l+1.
// h = x*cw+cb; 8x { h = gelu(LN_[100,4](h@Wl.T+bl)*g+b) }; XT[n][b] = h@Wl.T+bl
__global__ __launch_bounds__(64) void k_stageA(
    const float* __restrict__ x, const float* __restrict__ convw,
    const float* __restrict__ convb, const float* __restrict__ Wl,
    const float* __restrict__ bl, const float* __restrict__ lng,
    const float* __restrict__ lnb, float* __restrict__ XT)
{
  const int b = blockIdx.x;
  const int lane = threadIdx.x;
  const bool act = lane < 50;

  const float cw = convw[0], cb = convb[0];
  float W[4][4], B[4];
#pragma unroll
  for (int j = 0; j < 4; ++j) {
    B[j] = bl[j];
#pragma unroll
    for (int d = 0; d < 4; ++d) W[j][d] = Wl[j * 4 + d];
  }

  float h[2][4] = {{0.f,0.f,0.f,0.f},{0.f,0.f,0.f,0.f}};
  float gg[2][4] = {{0.f}}, eb[2][4] = {{0.f}};
  if (act) {
#pragma unroll
    for (int p = 0; p < 2; ++p) {
      const int r = lane * 2 + p;
      float4 xr = *(const float4*)(x + (b * SEQ + r) * 4);
      h[p][0] = fmaf(xr.x, cw, cb); h[p][1] = fmaf(xr.y, cw, cb);
      h[p][2] = fmaf(xr.z, cw, cb); h[p][3] = fmaf(xr.w, cw, cb);
      float4 gv = *(const float4*)(lng + r * 4);
      float4 bv = *(const float4*)(lnb + r * 4);
      gg[p][0] = gv.x; gg[p][1] = gv.y; gg[p][2] = gv.z; gg[p][3] = gv.w;
      eb[p][0] = bv.x; eb[p][1] = bv.y; eb[p][2] = bv.z; eb[p][3] = bv.w;
    }
  }
  for (int it = 0; it < NREP; ++it) {
    float y[2][4] = {{0.f,0.f,0.f,0.f},{0.f,0.f,0.f,0.f}};
    float s1 = 0.f, s2 = 0.f;
    if (act) {
#pragma unroll
      for (int p = 0; p < 2; ++p)
#pragma unroll
        for (int j = 0; j < 4; ++j) {
          float yy = B[j];
#pragma unroll
          for (int d = 0; d < 4; ++d) yy = fmaf(h[p][d], W[j][d], yy);
          y[p][j] = yy; s1 += yy; s2 = fmaf(yy, yy, s2);
        }
    }
    s1 = wsum(s1); s2 = wsum(s2);
    const float mean = s1 * (1.0f / 400.0f);
    const float var  = s2 * (1.0f / 400.0f) - mean * mean;
    const float rstd = rsqrtf(var + 1e-5f);
    if (act) {
#pragma unroll
      for (int p = 0; p < 2; ++p)
#pragma unroll
        for (int j = 0; j < 4; ++j) {
          float vv = fmaf((y[p][j] - mean) * rstd, gg[p][j], eb[p][j]);
          h[p][j] = 0.5f * vv * (1.0f + erff(vv * RSQRT2));
        }
    }
  }
  if (act) {
#pragma unroll
    for (int p = 0; p < 2; ++p) {
      const int r = lane * 2 + p;
      float yy[4];
#pragma unroll
      for (int j = 0; j < 4; ++j) {
        float a = B[j];
#pragma unroll
        for (int d = 0; d < 4; ++d) a = fmaf(h[p][d], W[j][d], a);
        yy[j] = a;
      }
      *(float4*)(XT + (r * BATCH + b) * 4) =
          make_float4(yy[0], yy[1], yy[2], yy[3]);
    }
  }
}

// ---------------------------------------------------------------- layer
// block = (column n, batch-half); 200 blocks x 512 threads. Full K/V for the
// column recomputed per block (cheap); attention + proj/LN1 + FFN + LN2 for
// its 128 rows. Layer 3 also does final linear + softmax -> out.
__global__ __launch_bounds__(512) void k_layer(
    const float* __restrict__ XTin, float* __restrict__ XTout,
    const float* __restrict__ Wa,  const float* __restrict__ ba,
    const float* __restrict__ Wo,  const float* __restrict__ bo,
    const float* __restrict__ W1l, const float* __restrict__ b1l,
    const float* __restrict__ W2l, const float* __restrict__ b2l,
    const float* __restrict__ g1l, const float* __restrict__ e1l,
    const float* __restrict__ g2l, const float* __restrict__ e2l,
    const float* __restrict__ Wl,  const float* __restrict__ bl,
    float* __restrict__ out, const int last)
{
  const int n      = blockIdx.x;        // column 0..99
  const int base_s = blockIdx.y * 128;  // batch half
  const int t      = threadIdx.x;       // 0..511
  const int lane   = t & 63;
  const int wv     = t >> 6;            // 0..7
  const int h      = t >> 7;            // head 0..3 (attn unit)
  const int qr     = t & 127;           // query row within half

  __shared__ float2 kv[4][256];       // full-column k,v per head
  __shared__ float  osm[4][128];      // attn out per head, own rows
  __shared__ float  x1s[128][4];      // post-LN1 rows
  __shared__ float  pacc[8][128][4];  // ffn partials
  __shared__ float  kred[8][2];       // per-wave k max/min

  // ---- K,V for the whole column (threads 0..255, s = t)
  if (t < 256) {
    float4 xr = *(const float4*)(XTin + (n * BATCH + t) * 4);
#pragma unroll
    for (int hh = 0; hh < 4; ++hh) {
      const float* wk = Wa + (4 + hh) * 4;
      const float* wp = Wa + (8 + hh) * 4;
      float k = ba[4+hh] + xr.x*wk[0] + xr.y*wk[1] + xr.z*wk[2] + xr.w*wk[3];
      float v = ba[8+hh] + xr.x*wp[0] + xr.y*wp[1] + xr.z*wp[2] + xr.w*wp[3];
      kv[hh][t] = make_float2(k, v);
    }
  }
  // ---- q for own unit (h, qr)
  float q;
  {
    float4 xr = *(const float4*)(XTin + (n * BATCH + base_s + qr) * 4);
    const float* wq = Wa + h * 4;
    q = ba[h] + xr.x*wq[0] + xr.y*wq[1] + xr.z*wq[2] + xr.w*wq[3];
  }
  __syncthreads();

  // ---- per-head k max/min (waves 2h, 2h+1 both cover head h)
  {
    float a = kv[h][qr].x, c = kv[h][qr + 128].x;
    float mx = fmaxf(a, c), mn = fminf(a, c);
#pragma unroll
    for (int o = 32; o > 0; o >>= 1) {
      mx = fmaxf(mx, __shfl_xor(mx, o, 64));
      mn = fminf(mn, __shfl_xor(mn, o, 64));
    }
    if (lane == 0) { kred[wv][0] = mx; kred[wv][1] = mn; }
  }
  __syncthreads();

  // ---- attention for own query
  {
    const float kmx = fmaxf(kred[2*h][0], kred[2*h+1][0]);
    const float kmn = fminf(kred[2*h][1], kred[2*h+1][1]);
    const float m = (q >= 0.f) ? q * kmx : q * kmn;  // exact max_t(q*k_t)
    float den0 = 0.f, den1 = 0.f, num0 = 0.f, num1 = 0.f;
#pragma unroll 4
    for (int t2 = 0; t2 < 256; t2 += 2) {
      float4 kk = *(const float4*)&kv[h][t2];   // (k0,v0,k1,v1)
      float p0 = __expf(fmaf(q, kk.x, -m));
      float p1 = __expf(fmaf(q, kk.z, -m));
      den0 += p0; num0 = fmaf(p0, kk.y, num0);
      den1 += p1; num1 = fmaf(p1, kk.w, num1);
    }
    osm[h][qr] = (num0 + num1) / (den0 + den1);
  }
  __syncthreads();

  // ---- Wout proj + residual + LN1 : thread -> (r = t>>2, d = t&3)
  {
    const int r = t >> 2, d = t & 3;
    const int g = n * BATCH + base_s + r;
    const float o0 = osm[0][r], o1 = osm[1][r], o2 = osm[2][r], o3 = osm[3][r];
    float rr = XTin[g * 4 + d] + bo[d]
             + o0 * Wo[d*4+0] + o1 * Wo[d*4+1] + o2 * Wo[d*4+2] + o3 * Wo[d*4+3];
    float sum = rr + __shfl_xor(rr, 1, 64); sum += __shfl_xor(sum, 2, 64);
    const float mean = 0.25f * sum;
    const float dv = rr - mean;
    float qq = dv * dv;
    float qs = qq + __shfl_xor(qq, 1, 64); qs += __shfl_xor(qs, 2, 64);
    const float rstd = rsqrtf(0.25f * qs + 1e-5f);
    x1s[r][d] = fmaf(dv * rstd, g1l[d], e1l[d]);
  }
  __syncthreads();

  // ---- FFN: wave wv owns f in [wv*256, wv*256+256); lane rows {lane, 64+lane}
  {
    const int fb = __builtin_amdgcn_readfirstlane(wv) * 256;
    const float xA0 = x1s[lane][0], xA1 = x1s[lane][1];
    const float xA2 = x1s[lane][2], xA3 = x1s[lane][3];
    const float xB0 = x1s[64+lane][0], xB1 = x1s[64+lane][1];
    const float xB2 = x1s[64+lane][2], xB3 = x1s[64+lane][3];
    float aA0=0.f,aA1=0.f,aA2=0.f,aA3=0.f;
    float aB0=0.f,aB1=0.f,aB2=0.f,aB3=0.f;
#pragma unroll 4
    for (int j = 0; j < 256; ++j) {
      const int f = fb + j;                      // wave-uniform -> s_load
      const float4 w1 = *(const float4*)(W1l + f * 4);
      const float bb  = b1l[f];
      const float w20 = W2l[f],           w21 = W2l[FFD + f];
      const float w22 = W2l[2*FFD + f],   w23 = W2l[3*FFD + f];
      float hA = fmaf(xA3, w1.w, fmaf(xA2, w1.z, fmaf(xA1, w1.y, fmaf(xA0, w1.x, bb))));
      hA = fmaxf(hA, 0.f);
      aA0 = fmaf(hA, w20, aA0); aA1 = fmaf(hA, w21, aA1);
      aA2 = fmaf(hA, w22, aA2); aA3 = fmaf(hA, w23, aA3);
      float hB = fmaf(xB3, w1.w, fmaf(xB2, w1.z, fmaf(xB1, w1.y, fmaf(xB0, w1.x, bb))));
      hB = fmaxf(hB, 0.f);
      aB0 = fmaf(hB, w20, aB0); aB1 = fmaf(hB, w21, aB1);
      aB2 = fmaf(hB, w22, aB2); aB3 = fmaf(hB, w23, aB3);
    }
    *(float4*)&pacc[wv][lane][0]      = make_float4(aA0, aA1, aA2, aA3);
    *(float4*)&pacc[wv][64 + lane][0] = make_float4(aB0, aB1, aB2, aB3);
  }
  __syncthreads();

  // ---- reduce + residual + LN2 : thread -> (r, d)
  {
    const int r = t >> 2, d = t & 3;
    float s8 = b2l[d];
#pragma unroll
    for (int w = 0; w < 8; ++w) s8 += pacc[w][r][d];
    float val = x1s[r][d] + s8;
    float sum = val + __shfl_xor(val, 1, 64); sum += __shfl_xor(sum, 2, 64);
    const float mean = 0.25f * sum;
    const float dv = val - mean;
    float qq = dv * dv;
    float qs = qq + __shfl_xor(qq, 1, 64); qs += __shfl_xor(qs, 2, 64);
    const float rstd = rsqrtf(0.25f * qs + 1e-5f);
    const float res = fmaf(dv * rstd, g2l[d], e2l[d]);
    if (!last) XTout[(n * BATCH + base_s + r) * 4 + d] = res;
    else       x1s[r][d] = res;
  }

  // ---- layer 3 only: final linear + softmax over d
  if (last) {
    __syncthreads();
    const int r = t >> 2, j = t & 3;
    const float y = fmaf(x1s[r][3], Wl[j*4+3], fmaf(x1s[r][2], Wl[j*4+2],
                    fmaf(x1s[r][1], Wl[j*4+1], fmaf(x1s[r][0], Wl[j*4+0], bl[j]))));
    float mx = fmaxf(y, __shfl_xor(y, 1, 64)); mx = fmaxf(mx, __shfl_xor(mx, 2, 64));
    const float e = __expf(y - mx);
    float se = e + __shfl_xor(e, 1, 64); se += __shfl_xor(se, 2, 64);
    out[((base_s + r) * SEQ + n) * 4 + j] = e / se;
  }
}

// ---------------------------------------------------------------- launch
extern "C" void kernel_launch(void* const* d_in, const int* in_sizes, int n_in,
                              void* d_out, int out_size, void* d_ws, size_t ws_size,
                              hipStream_t stream)
{
  const float* x     = (const float*)d_in[0];
  const float* convw = (const float*)d_in[1];
  const float* convb = (const float*)d_in[2];
  const float* Wl    = (const float*)d_in[3];
  const float* bl    = (const float*)d_in[4];
  const float* lng   = (const float*)d_in[5];
  const float* lnb   = (const float*)d_in[6];
  const float* Win   = (const float*)d_in[7];
  const float* bi    = (const float*)d_in[8];
  const float* Wout  = (const float*)d_in[9];
  const float* bout  = (const float*)d_in[10];
  const float* W1    = (const float*)d_in[11];
  const float* b1    = (const float*)d_in[12];
  const float* W2    = (const float*)d_in[13];
  const float* b2    = (const float*)d_in[14];
  const float* g1    = (const float*)d_in[15];
  const float* be1   = (const float*)d_in[16];
  const float* g2    = (const float*)d_in[17];
  const float* be2   = (const float*)d_in[18];

  float* XT0 = (float*)d_ws;            // [100][256][4]
  float* XT1 = XT0 + SEQ * BATCH * 4;

  k_stageA<<<BATCH, 64, 0, stream>>>(x, convw, convb, Wl, bl, lng, lnb, XT0);
  for (int l = 0; l < 4; ++l) {
    const float* in  = (l & 1) ? XT1 : XT0;
    float*       outb= (l & 1) ? XT0 : XT1;
    k_layer<<<dim3(SEQ, 2), 512, 0, stream>>>(
        in, outb,
        Win + l * 48, bi + l * 12, Wout + l * 16, bout + l * 4,
        W1 + l * FFD * 4, b1 + l * FFD, W2 + l * 4 * FFD, b2 + l * 4,
        g1 + l * 4, be1 + l * 4, g2 + l * 4, be2 + l * 4,
        Wl, bl, (float*)d_out, (l == 3) ? 1 : 0);
  }
}

// Round 6
// 121.726 us; speedup vs baseline: 3.5345x; 1.0890x over previous
//
#include <hip/hip_runtime.h>
#include <math.h>

#define SEQ   100
#define BATCH 256
#define NREP  8
#define FFD   2048
#define RSQRT2 0.70710678118654752440f

__device__ __forceinline__ float wsum(float v) {
#pragma unroll
  for (int o = 32; o > 0; o >>= 1) v += __shfl_xor(v, o, 64);
  return v;
}

// ---------------------------------------------------------------- stage A
__global__ __launch_bounds__(64) void k_stageA(
    const float* __restrict__ x, const float* __restrict__ convw,
    const float* __restrict__ convb, const float* __restrict__ Wl,
    const float* __restrict__ bl, const float* __restrict__ lng,
    const float* __restrict__ lnb, float* __restrict__ XT)
{
  const int b = blockIdx.x;
  const int lane = threadIdx.x;
  const bool act = lane < 50;

  const float cw = convw[0], cb = convb[0];
  float W[4][4], B[4];
#pragma unroll
  for (int j = 0; j < 4; ++j) {
    B[j] = bl[j];
#pragma unroll
    for (int d = 0; d < 4; ++d) W[j][d] = Wl[j * 4 + d];
  }

  float h[2][4] = {{0.f,0.f,0.f,0.f},{0.f,0.f,0.f,0.f}};
  float gg[2][4] = {{0.f}}, eb[2][4] = {{0.f}};
  if (act) {
#pragma unroll
    for (int p = 0; p < 2; ++p) {
      const int r = lane * 2 + p;
      float4 xr = *(const float4*)(x + (b * SEQ + r) * 4);
      h[p][0] = fmaf(xr.x, cw, cb); h[p][1] = fmaf(xr.y, cw, cb);
      h[p][2] = fmaf(xr.z, cw, cb); h[p][3] = fmaf(xr.w, cw, cb);
      float4 gv = *(const float4*)(lng + r * 4);
      float4 bv = *(const float4*)(lnb + r * 4);
      gg[p][0] = gv.x; gg[p][1] = gv.y; gg[p][2] = gv.z; gg[p][3] = gv.w;
      eb[p][0] = bv.x; eb[p][1] = bv.y; eb[p][2] = bv.z; eb[p][3] = bv.w;
    }
  }
  for (int it = 0; it < NREP; ++it) {
    float y[2][4] = {{0.f,0.f,0.f,0.f},{0.f,0.f,0.f,0.f}};
    float s1 = 0.f, s2 = 0.f;
    if (act) {
#pragma unroll
      for (int p = 0; p < 2; ++p)
#pragma unroll
        for (int j = 0; j < 4; ++j) {
          float yy = B[j];
#pragma unroll
          for (int d = 0; d < 4; ++d) yy = fmaf(h[p][d], W[j][d], yy);
          y[p][j] = yy; s1 += yy; s2 = fmaf(yy, yy, s2);
        }
    }
    s1 = wsum(s1); s2 = wsum(s2);
    const float mean = s1 * (1.0f / 400.0f);
    const float var  = s2 * (1.0f / 400.0f) - mean * mean;
    const float rstd = rsqrtf(var + 1e-5f);
    if (act) {
#pragma unroll
      for (int p = 0; p < 2; ++p)
#pragma unroll
        for (int j = 0; j < 4; ++j) {
          float vv = fmaf((y[p][j] - mean) * rstd, gg[p][j], eb[p][j]);
          h[p][j] = 0.5f * vv * (1.0f + erff(vv * RSQRT2));
        }
    }
  }
  if (act) {
#pragma unroll
    for (int p = 0; p < 2; ++p) {
      const int r = lane * 2 + p;
      float yy[4];
#pragma unroll
      for (int j = 0; j < 4; ++j) {
        float a = B[j];
#pragma unroll
        for (int d = 0; d < 4; ++d) a = fmaf(h[p][d], W[j][d], a);
        yy[j] = a;
      }
      *(float4*)(XT + (r * BATCH + b) * 4) =
          make_float4(yy[0], yy[1], yy[2], yy[3]);
    }
  }
}

// ---------------------------------------------------------------- layer
// block = (column n, batch-half); 200 blocks x 512 threads.
// FFN weights staged to LDS in 4 passes of 512 f, with next-pass global
// loads issued before current-pass compute (latency hidden under FMAs).
__global__ __launch_bounds__(512) void k_layer(
    const float* __restrict__ XTin, float* __restrict__ XTout,
    const float* __restrict__ Wa,  const float* __restrict__ ba,
    const float* __restrict__ Wo,  const float* __restrict__ bo,
    const float* __restrict__ W1l, const float* __restrict__ b1l,
    const float* __restrict__ W2l, const float* __restrict__ b2l,
    const float* __restrict__ g1l, const float* __restrict__ e1l,
    const float* __restrict__ g2l, const float* __restrict__ e2l,
    const float* __restrict__ Wl,  const float* __restrict__ bl,
    float* __restrict__ out, const int last)
{
  const int n      = blockIdx.x;        // column 0..99
  const int base_s = blockIdx.y * 128;  // batch half
  const int t      = threadIdx.x;       // 0..511
  const int lane   = t & 63;
  const int wv     = t >> 6;            // 0..7
  const int h      = t >> 7;            // head 0..3 (uniform per wave)
  const int qr     = t & 127;           // query row within half

  __shared__ __align__(16) float wbuf[512][12]; // packed ffn weights (24 KB)
  __shared__ float2 kv[4][256];       // full-column k,v per head (8 KB)
  __shared__ float  osm[4][128];      // attn out per head
  __shared__ float  x1s[128][4];      // post-LN1 rows
  __shared__ float  pacc[8][128][4];  // ffn partials (16 KB)
  __shared__ float  kred[8][2];       // per-wave k max/min

  // ---- issue staging loads for ffn pass 0 (hide under qkv+attn)
  float4 s_w1; float s_b1, s_w20, s_w21, s_w22, s_w23;
  {
    const int f = t;
    s_w1  = *(const float4*)(W1l + f * 4);
    s_b1  = b1l[f];
    s_w20 = W2l[f];           s_w21 = W2l[FFD + f];
    s_w22 = W2l[2 * FFD + f]; s_w23 = W2l[3 * FFD + f];
  }

  // ---- K,V for the whole column: thread (pair = t>>8, s = t&255)
  {
    const int s = t & 255, pr = t >> 8;
    float4 xr = *(const float4*)(XTin + (n * BATCH + s) * 4);
#pragma unroll
    for (int i = 0; i < 2; ++i) {
      const int hh = pr * 2 + i;
      const float* wk = Wa + (4 + hh) * 4;
      const float* wp = Wa + (8 + hh) * 4;
      float k = ba[4+hh] + xr.x*wk[0] + xr.y*wk[1] + xr.z*wk[2] + xr.w*wk[3];
      float v = ba[8+hh] + xr.x*wp[0] + xr.y*wp[1] + xr.z*wp[2] + xr.w*wp[3];
      kv[hh][s] = make_float2(k, v);
    }
  }
  // ---- q for own (h, qr)
  float q;
  {
    float4 xr = *(const float4*)(XTin + (n * BATCH + base_s + qr) * 4);
    const float* wq = Wa + h * 4;
    q = ba[h] + xr.x*wq[0] + xr.y*wq[1] + xr.z*wq[2] + xr.w*wq[3];
  }
  __syncthreads();

  // ---- per-head k max/min (waves 2h,2h+1 cover head h)
  {
    float a = kv[h][qr].x, c = kv[h][qr + 128].x;
    float mx = fmaxf(a, c), mn = fminf(a, c);
#pragma unroll
    for (int o = 32; o > 0; o >>= 1) {
      mx = fmaxf(mx, __shfl_xor(mx, o, 64));
      mn = fminf(mn, __shfl_xor(mn, o, 64));
    }
    if (lane == 0) { kred[wv][0] = mx; kred[wv][1] = mn; }
  }
  __syncthreads();

  // ---- attention (4 chains, broadcast b128 reads)
  {
    const float kmx = fmaxf(kred[2*h][0], kred[2*h+1][0]);
    const float kmn = fminf(kred[2*h][1], kred[2*h+1][1]);
    const float m = (q >= 0.f) ? q * kmx : q * kmn;  // exact max_t(q*k_t)
    float d0=0.f,d1=0.f,d2=0.f,d3=0.f,n0=0.f,n1=0.f,n2=0.f,n3=0.f;
#pragma unroll 4
    for (int t2 = 0; t2 < 256; t2 += 8) {
      float4 a = *(const float4*)&kv[h][t2];      // (k,v,k,v)
      float4 b = *(const float4*)&kv[h][t2+2];
      float4 c = *(const float4*)&kv[h][t2+4];
      float4 e = *(const float4*)&kv[h][t2+6];
      float p0 = __expf(fmaf(q, a.x, -m)); d0 += p0; n0 = fmaf(p0, a.y, n0);
      float p1 = __expf(fmaf(q, a.z, -m)); d1 += p1; n1 = fmaf(p1, a.w, n1);
      float p2 = __expf(fmaf(q, b.x, -m)); d2 += p2; n2 = fmaf(p2, b.y, n2);
      float p3 = __expf(fmaf(q, b.z, -m)); d3 += p3; n3 = fmaf(p3, b.w, n3);
      p0 = __expf(fmaf(q, c.x, -m)); d0 += p0; n0 = fmaf(p0, c.y, n0);
      p1 = __expf(fmaf(q, c.z, -m)); d1 += p1; n1 = fmaf(p1, c.w, n1);
      p2 = __expf(fmaf(q, e.x, -m)); d2 += p2; n2 = fmaf(p2, e.y, n2);
      p3 = __expf(fmaf(q, e.z, -m)); d3 += p3; n3 = fmaf(p3, e.w, n3);
    }
    osm[h][qr] = (n0+n1+n2+n3) / (d0+d1+d2+d3);
  }
  __syncthreads();

  // ---- Wout proj + residual + LN1 : thread -> (r = t>>2, d = t&3)
  {
    const int r = t >> 2, d = t & 3;
    const int g = n * BATCH + base_s + r;
    const float o0 = osm[0][r], o1 = osm[1][r], o2 = osm[2][r], o3 = osm[3][r];
    float rr = XTin[g * 4 + d] + bo[d]
             + o0 * Wo[d*4+0] + o1 * Wo[d*4+1] + o2 * Wo[d*4+2] + o3 * Wo[d*4+3];
    float sum = rr + __shfl_xor(rr, 1, 64); sum += __shfl_xor(sum, 2, 64);
    const float mean = 0.25f * sum;
    const float dv = rr - mean;
    float qq = dv * dv;
    float qs = qq + __shfl_xor(qq, 1, 64); qs += __shfl_xor(qs, 2, 64);
    const float rstd = rsqrtf(0.25f * qs + 1e-5f);
    x1s[r][d] = fmaf(dv * rstd, g1l[d], e1l[d]);
  }
  __syncthreads();

  // ---- FFN: 4 passes of 512 f; wave wv covers f_local [wv*64, wv*64+64)
  const float xA0 = x1s[lane][0],    xA1 = x1s[lane][1];
  const float xA2 = x1s[lane][2],    xA3 = x1s[lane][3];
  const float xB0 = x1s[64+lane][0], xB1 = x1s[64+lane][1];
  const float xB2 = x1s[64+lane][2], xB3 = x1s[64+lane][3];
  float aA0=0.f,aA1=0.f,aA2=0.f,aA3=0.f;
  float aB0=0.f,aB1=0.f,aB2=0.f,aB3=0.f;

  for (int p = 0; p < 4; ++p) {
    __syncthreads();   // wbuf free (previous pass consumed)
    *(float4*)&wbuf[t][0] = s_w1;
    *(float4*)&wbuf[t][4] = make_float4(s_b1, s_w20, s_w21, s_w22);
    wbuf[t][8] = s_w23;
    if (p < 3) {       // issue next pass loads; latency hides under compute
      const int f = (p + 1) * 512 + t;
      s_w1  = *(const float4*)(W1l + f * 4);
      s_b1  = b1l[f];
      s_w20 = W2l[f];           s_w21 = W2l[FFD + f];
      s_w22 = W2l[2 * FFD + f]; s_w23 = W2l[3 * FFD + f];
    }
    __syncthreads();   // wbuf ready
    const int fb = wv * 64;
#pragma unroll 4
    for (int j = 0; j < 64; ++j) {
      const int fl = fb + j;
      const float4 w1 = *(const float4*)&wbuf[fl][0];
      const float4 wb = *(const float4*)&wbuf[fl][4];  // {b1, w20, w21, w22}
      const float w23 = wbuf[fl][8];
      float hA = fmaf(xA3, w1.w, fmaf(xA2, w1.z, fmaf(xA1, w1.y, fmaf(xA0, w1.x, wb.x))));
      hA = fmaxf(hA, 0.f);
      aA0 = fmaf(hA, wb.y, aA0); aA1 = fmaf(hA, wb.z, aA1);
      aA2 = fmaf(hA, wb.w, aA2); aA3 = fmaf(hA, w23, aA3);
      float hB = fmaf(xB3, w1.w, fmaf(xB2, w1.z, fmaf(xB1, w1.y, fmaf(xB0, w1.x, wb.x))));
      hB = fmaxf(hB, 0.f);
      aB0 = fmaf(hB, wb.y, aB0); aB1 = fmaf(hB, wb.z, aB1);
      aB2 = fmaf(hB, wb.w, aB2); aB3 = fmaf(hB, w23, aB3);
    }
  }
  *(float4*)&pacc[wv][lane][0]      = make_float4(aA0, aA1, aA2, aA3);
  *(float4*)&pacc[wv][64 + lane][0] = make_float4(aB0, aB1, aB2, aB3);
  __syncthreads();

  // ---- reduce + residual + LN2 : thread -> (r, d)
  {
    const int r = t >> 2, d = t & 3;
    float s8 = b2l[d];
#pragma unroll
    for (int w = 0; w < 8; ++w) s8 += pacc[w][r][d];
    float val = x1s[r][d] + s8;
    float sum = val + __shfl_xor(val, 1, 64); sum += __shfl_xor(sum, 2, 64);
    const float mean = 0.25f * sum;
    const float dv = val - mean;
    float qq = dv * dv;
    float qs = qq + __shfl_xor(qq, 1, 64); qs += __shfl_xor(qs, 2, 64);
    const float rstd = rsqrtf(0.25f * qs + 1e-5f);
    const float res = fmaf(dv * rstd, g2l[d], e2l[d]);
    if (!last) XTout[(n * BATCH + base_s + r) * 4 + d] = res;
    else       x1s[r][d] = res;
  }

  // ---- layer 3 only: final linear + softmax over d
  if (last) {
    __syncthreads();
    const int r = t >> 2, j = t & 3;
    const float y = fmaf(x1s[r][3], Wl[j*4+3], fmaf(x1s[r][2], Wl[j*4+2],
                    fmaf(x1s[r][1], Wl[j*4+1], fmaf(x1s[r][0], Wl[j*4+0], bl[j]))));
    float mx = fmaxf(y, __shfl_xor(y, 1, 64)); mx = fmaxf(mx, __shfl_xor(mx, 2, 64));
    const float e = __expf(y - mx);
    float se = e + __shfl_xor(e, 1, 64); se += __shfl_xor(se, 2, 64);
    out[((base_s + r) * SEQ + n) * 4 + j] = e / se;
  }
}

// ---------------------------------------------------------------- launch
extern "C" void kernel_launch(void* const* d_in, const int* in_sizes, int n_in,
                              void* d_out, int out_size, void* d_ws, size_t ws_size,
                              hipStream_t stream)
{
  const float* x     = (const float*)d_in[0];
  const float* convw = (const float*)d_in[1];
  const float* convb = (const float*)d_in[2];
  const float* Wl    = (const float*)d_in[3];
  const float* bl    = (const float*)d_in[4];
  const float* lng   = (const float*)d_in[5];
  const float* lnb   = (const float*)d_in[6];
  const float* Win   = (const float*)d_in[7];
  const float* bi    = (const float*)d_in[8];
  const float* Wout  = (const float*)d_in[9];
  const float* bout  = (const float*)d_in[10];
  const float* W1    = (const float*)d_in[11];
  const float* b1    = (const float*)d_in[12];
  const float* W2    = (const float*)d_in[13];
  const float* b2    = (const float*)d_in[14];
  const float* g1    = (const float*)d_in[15];
  const float* be1   = (const float*)d_in[16];
  const float* g2    = (const float*)d_in[17];
  const float* be2   = (const float*)d_in[18];

  float* XT0 = (float*)d_ws;            // [100][256][4]
  float* XT1 = XT0 + SEQ * BATCH * 4;

  k_stageA<<<BATCH, 64, 0, stream>>>(x, convw, convb, Wl, bl, lng, lnb, XT0);
  for (int l = 0; l < 4; ++l) {
    const float* in  = (l & 1) ? XT1 : XT0;
    float*       outb= (l & 1) ? XT0 : XT1;
    k_layer<<<dim3(SEQ, 2), 512, 0, stream>>>(
        in, outb,
        Win + l * 48, bi + l * 12, Wout + l * 16, bout + l * 4,
        W1 + l * FFD * 4, b1 + l * FFD, W2 + l * 4 * FFD, b2 + l * 4,
        g1 + l * 4, be1 + l * 4, g2 + l * 4, be2 + l * 4,
        Wl, bl, (float*)d_out, (l == 3) ? 1 : 0);
  }
}